// Round 22
// baseline (97.238 us; speedup 1.0000x reference)
//
#include <hip/hip_runtime.h>

typedef _Float16 f16;
typedef _Float16 f16x2 __attribute__((ext_vector_type(2)));
typedef _Float16 f16x4 __attribute__((ext_vector_type(4)));
typedef _Float16 f16x8 __attribute__((ext_vector_type(8)));
typedef float    f32x16 __attribute__((ext_vector_type(16)));

#define KW 31
#define R  15
#define NP 32
#define HH 512
#define WW 512
#define NB 4

#define TW 32            // output tile width (px)
#define TH 32            // output tile height
#define EXT_X 62         // data cols 0..61; cols 62..71 zero
#define SX 72            // tile row stride (f16)
#define EXT_Y 63         // 62 data rows + 1 zero row
#define GB 32            // weight table base: idx = GB + tap
#define GT_S 98          // per-copy row length (f16), R17-proven layout

// LDS: tile 27216 + gTh2 12544 + pl8 1024 = 40784 -> 40960 alloc -> 4 blocks/CU
__global__ __launch_bounds__(256, 1) void defocus_kernel(
    const float* __restrict__ sharp, const float* __restrict__ coc_map,
    float* __restrict__ out)
{
    __shared__ __align__(16) f16 tile[3][EXT_Y][SX];
    __shared__ __align__(16) f16 gTh2[NP][2][GT_S];    // [plane][parity copy][idx]
    __shared__ unsigned char pl8[TH][TW];

    const int tid = threadIdx.x;
    const int bx = blockIdx.x, by = blockIdx.y, bb = blockIdx.z;

    // ---- phase 1a: zero weight table (256-thread parallel) ----
    for (int i = tid; i < NP * GT_S; i += 256)     // NP*2*GT_S f16 = NP*GT_S f16x2
        ((f16x2*)gTh2)[i] = (f16x2){(f16)0.0f, (f16)0.0f};
    __syncthreads();

    // ---- phase 1b: copy0 weights, 8 threads per plane, f32 exp ----
    {
        const int p = tid >> 3, sub = tid & 7;
        const double step = 50.0 / 31.0;
        const float pv = (p == 31) ? 50.0f : (float)((double)p * step);
        if (pv < 0.5f) {
            if (sub == 0) gTh2[p][0][GB + R] = (f16)1.0f;
        } else {
            const double coc = (double)pv;
            int k = (int)(2.0 * coc + 1.0);
            if ((k & 1) == 0) k += 1;
            if (k > KW) k = KW;
            const int half = k >> 1;
            const float sigma = (float)(coc / 2.355);
            const float inv2s2 = 1.0f / (2.0f * sigma * sigma);
            float w[4]; float s = 0.0f;
            #pragma unroll
            for (int m = 0; m < 4; ++m) {
                const int t = sub + 8 * m;
                float val = 0.0f;
                if (t < k) {
                    const float cc = (float)(t - half);
                    val = __expf(-(cc * cc) * inv2s2);
                }
                w[m] = val; s += val;
            }
            s += __shfl_xor(s, 1, 64);              // 8-lane group sum
            s += __shfl_xor(s, 2, 64);
            s += __shfl_xor(s, 4, 64);
            const float inv = 1.0f / s;
            #pragma unroll
            for (int m = 0; m < 4; ++m) {
                const int t = sub + 8 * m;
                if (t < k) gTh2[p][0][GB + (R - half + t)] = (f16)(w[m] * inv);
            }
        }
    }
    __syncthreads();

    // ---- phase 1c: copy1 = copy0 shifted 1 (256-thread parallel) ----
    for (int idx = tid; idx < NP * GT_S; idx += 256) {
        const int p = idx / GT_S, i = idx - p * GT_S;
        gTh2[p][1][i] = (i < GT_S - 1) ? gTh2[p][0][i + 1] : (f16)0.0f;
    }

    // ---- phase 2a: plane selection vs COMPILE-TIME-FOLDED boundaries ----
    {
        const int row = tid >> 3;
        const int x4  = (tid & 7) * 4;
        const float4 c4 = *(const float4*)&coc_map[((size_t)bb * HH + by * TH + row) * WW + bx * TW + x4];
        const float cv[4] = {c4.x, c4.y, c4.z, c4.w};
        int pp[4] = {0, 0, 0, 0};
        #pragma unroll
        for (int k = 0; k < KW; ++k) {              // all literal arithmetic -> folded
            const double step = 50.0 / 31.0;
            const float pa = (float)((double)k * step);
            const float pb = (k == 30) ? 50.0f : (float)((double)(k + 1) * step);
            const float b = (pa + pb) * 0.5f;
            pp[0] += (cv[0] > b) ? 1 : 0;
            pp[1] += (cv[1] > b) ? 1 : 0;
            pp[2] += (cv[2] > b) ? 1 : 0;
            pp[3] += (cv[3] > b) ? 1 : 0;
        }
        *(uchar4*)&pl8[row][x4] = make_uchar4((unsigned char)pp[0], (unsigned char)pp[1],
                                              (unsigned char)pp[2], (unsigned char)pp[3]);
    }

    // ---- phase 2b: stage tile as f16, 4 px/iteration (f32x4 -> ds_write_b64) ----
    {
        const int x0 = bx * TW - R, y0 = by * TH - R;
        for (int idx = tid; idx < 3 * EXT_Y * (SX / 4); idx += 256) {
            const int qw = idx % (SX / 4);              // 4-px group, 18 per row
            const int rr = (idx / (SX / 4)) % EXT_Y;
            const int ch = idx / ((SX / 4) * EXT_Y);
            const int gy = y0 + rr;
            const int gx = x0 + 4 * qw;
            f16x4 h = {(f16)0.0f, (f16)0.0f, (f16)0.0f, (f16)0.0f};
            if (rr < 62 && (unsigned)gy < HH) {
                const float* src = &sharp[(((size_t)bb * 3 + ch) * HH + gy) * WW];
                if (4 * qw + 3 < EXT_X && gx >= 0 && gx + 3 < WW) {
                    const float4 v = *(const float4*)&src[gx];   // interior fast path
                    h.x = (f16)v.x; h.y = (f16)v.y; h.z = (f16)v.z; h.w = (f16)v.w;
                } else {
                    #pragma unroll
                    for (int i = 0; i < 4; ++i)
                        if (4 * qw + i < EXT_X && (unsigned)(gx + i) < WW)
                            h[i] = (f16)src[gx + i];
                }
            }
            *(f16x4*)&tile[ch][rr][4 * qw] = h;             // 8B-aligned
        }
    }
    __syncthreads();

    // ---- phase 3: one 32x32 GEMM (K=64) per (row, channel) ----
    // S[dy][px] = sum_k tile[r+dy][k] * g_{plane(px)}[k - px]
    // A: m=lane&31 (dy), k=(lane>>5)*8+j (+16kc). C/D: col=lane&31 (px),
    // row=(reg&3)+8(reg>>2)+4(lane>>5) (dy). Partials split only across h=lane>>5.
    const int lid = tid & 63, wv = tid >> 6;
    const int c32 = lid & 31, h = lid >> 5;
    const int cp = c32 & 1;
    const int dwb0 = (GB + 8 * h - c32) >> 1;

    union U8 { f16x2 h2[4]; f16x8 h8; };

    #pragma unroll 4
    for (int r = wv; r < TH; r += 4) {            // 32 tasks: one per row
        const int pm = pl8[r][c32];
        const f16* tab = &gTh2[pm][cp][0];

        U8 bf[4];
        #pragma unroll
        for (int kc = 0; kc < 4; ++kc)
            #pragma unroll
            for (int n = 0; n < 4; ++n)
                bf[kc].h2[n] = *(const f16x2*)&tab[2 * (dwb0 + 8 * kc + n)];

        f16x4 wy[4];
        #pragma unroll
        for (int a = 0; a < 4; ++a)
            wy[a] = *(const f16x4*)&gTh2[pm][0][GB + 8 * a + 4 * h];

        float o[3];
        #pragma unroll
        for (int ch = 0; ch < 3; ++ch) {
            const f16* ap = &tile[ch][r + c32][8 * h];
            f32x16 acc;
            #pragma unroll
            for (int i = 0; i < 16; ++i) acc[i] = 0.0f;
            acc = __builtin_amdgcn_mfma_f32_32x32x16_f16(*(const f16x8*)(ap     ), bf[0].h8, acc, 0, 0, 0);
            acc = __builtin_amdgcn_mfma_f32_32x32x16_f16(*(const f16x8*)(ap + 16), bf[1].h8, acc, 0, 0, 0);
            acc = __builtin_amdgcn_mfma_f32_32x32x16_f16(*(const f16x8*)(ap + 32), bf[2].h8, acc, 0, 0, 0);
            acc = __builtin_amdgcn_mfma_f32_32x32x16_f16(*(const f16x8*)(ap + 48), bf[3].h8, acc, 0, 0, 0);
            float s = 0.0f;
            #pragma unroll
            for (int a = 0; a < 4; ++a)
                #pragma unroll
                for (int b = 0; b < 4; ++b)
                    s = fmaf((float)wy[a][b], acc[4 * a + b], s);
            o[ch] = s;
        }

        #pragma unroll
        for (int ch = 0; ch < 3; ++ch) o[ch] += __shfl_xor(o[ch], 32, 64);

        if (h == 0) {
            const int oy = by * TH + r;
            const int ox = bx * TW + c32;
            #pragma unroll
            for (int ch = 0; ch < 3; ++ch)
                out[(((size_t)bb * 3 + ch) * HH + oy) * WW + ox] = o[ch];
        }
    }
}

extern "C" void kernel_launch(void* const* d_in, const int* in_sizes, int n_in,
                              void* d_out, int out_size, void* d_ws, size_t ws_size,
                              hipStream_t stream) {
    const float* sharp = (const float*)d_in[0];
    const float* coc   = (const float*)d_in[1];
    float* outp        = (float*)d_out;
    dim3 grid(WW / TW, HH / TH, NB);
    defocus_kernel<<<grid, dim3(256), 0, stream>>>(sharp, coc, outp);
}